// Round 20
// baseline (452.727 us; speedup 1.0000x reference)
//
#include <hip/hip_runtime.h>

#define J 17
#define JP 18
#define VO 289            // 17*17
#define NB 8192
#define DIN 2048
#define EPSB 1e-5f
#define KC 512            // conv0: k-floats per staged chunk (2KB per row)
#define RT 32             // conv0: rows per block
#define NCH 68            // 17*2048/512 chunks per row

typedef __attribute__((ext_vector_type(8))) short bf16x8;
typedef __attribute__((ext_vector_type(4))) float f32x4;
typedef __attribute__((ext_vector_type(4))) float f32x4v;

// adjacency (incl. self) as bitmasks, from SKEL
__device__ __constant__ unsigned ADJM[J] = {
  0x7u, 0xFu, 0x17u, 0x2Au, 0x54u, 0x8E8u, 0x1170u, 0x2A0u, 0x540u,
  0x280u, 0x500u, 0x3820u, 0x5840u, 0xA800u, 0x15000u, 0xA000u, 0x14000u};

__device__ inline unsigned short f2bf(float x){
  unsigned u = __float_as_uint(x);
  return (unsigned short)((u + 0x7fffu + ((u>>16)&1u)) >> 16);   // RNE
}
__device__ inline float bf2f(unsigned short u){
  return __uint_as_float(((unsigned)u)<<16);
}

__global__ void zero_stats(float* p, int n) {
  int i = blockIdx.x*blockDim.x + threadIdx.x;
  int stride = gridDim.x*blockDim.x;
  for (; i < n; i += stride) p[i] = 0.f;
}

// -------- prepass: W0 -> Wp fragment-major [v][k/8][col 0..16][8]
__global__ __launch_bounds__(256) void wconv_kernel(
    const float* __restrict__ W0, unsigned short* __restrict__ Wp)
{
  int t = blockIdx.x*256 + threadIdx.x;
  int v = t >> 11, k = t & 2047;
  const float* src = W0 + (size_t)t*J;
  unsigned short* dst = Wp + (((size_t)v*256 + (k>>3))*17)*8 + (k&7);
  #pragma unroll
  for (int o=0;o<J;++o)  dst[o*8] = f2bf(src[o]);
}

// -------- prepass: chain W fragments for ALL 8 stages (MFMA B layout)
__global__ __launch_bounds__(256) void wfrag_kernel(
    const float* __restrict__ Wr, unsigned short* __restrict__ WfA,
    unsigned short* __restrict__ WfB)
{
  int t = blockIdx.x*256 + threadIdx.x;
  if (t < 8*17*64) {
    int s = t/(17*64), rem = t - s*17*64, v = rem>>6, ll = rem&63;
    int c = ll&15, o8 = ll>>4;
    unsigned short* dst = WfA + (size_t)t*8;
    const float* w = Wr + ((size_t)(s*J + v)*J)*J;
    #pragma unroll
    for (int j=0;j<8;++j){ int d=o8*8+j; dst[j] = (d<J) ? f2bf(w[(size_t)d*J + c]) : (unsigned short)0; }
  }
  if (t < 8*17*4) {
    int s = t/(17*4), rem = t - s*17*4, v = rem>>2, o8 = rem&3;
    unsigned short* dst = WfB + (size_t)t*8;
    const float* w = Wr + ((size_t)(s*J + v)*J)*J;
    #pragma unroll
    for (int j=0;j<8;++j){ int d=o8*8+j; dst[j] = (d<J) ? f2bf(w[(size_t)d*J + 16]) : (unsigned short)0; }
  }
}

// -------- conv0 v9: wave-owns-4-rows staging (1KB contiguous bursts, 2048 streams)
// + B register prefetch + single-pass epilogue (r19 otherwise)
__global__ __launch_bounds__(512) void conv0_kernel(
    const float* __restrict__ feat, const unsigned short* __restrict__ Wp,
    const float* __restrict__ b0, unsigned short* __restrict__ C,
    float* __restrict__ stat0)
{
  const int tid = threadIdx.x, w = tid>>6, l = tid&63;
  const int lo = l&15, oc = l>>4;
  const int rowBase = blockIdx.x*RT;

  __shared__ __align__(16) unsigned short Ab[2][RT*KC];   // 64 KB
  __shared__ float red[8][4][256];                        // 32 KB single-pass reduce
  __shared__ float bS[VO], bQ[VO];

  for (int i=tid;i<VO;i+=512){ bS[i]=0.f; bQ[i]=0.f; }

  f32x4 acc00 = (f32x4){0.f,0.f,0.f,0.f};
  f32x4 acc01 = (f32x4){0.f,0.f,0.f,0.f};
  f32x4 acc10 = (f32x4){0.f,0.f,0.f,0.f};
  f32x4 acc11 = (f32x4){0.f,0.f,0.f,0.f};

  const float* fbase = feat + (size_t)rowBase*(J*DIN);
  f32x4v ld[8];

  // wave w owns rows 4w..4w+3; lane l covers floats [l*8, l*8+8) of each row's 2KB chunk
  auto issue = [&](int c){
    #pragma unroll
    for (int i=0;i<4;++i){
      const float* src = fbase + (size_t)(w*4+i)*(J*DIN) + c*KC + l*8;
      ld[i*2+0] = __builtin_nontemporal_load((const f32x4v*)src);
      ld[i*2+1] = __builtin_nontemporal_load((const f32x4v*)src + 1);
    }
  };
  auto writeLDS = [&](int buf){
    #pragma unroll
    for (int i=0;i<4;++i){
      const int r = w*4 + i;
      #pragma unroll
      for (int j=0;j<2;++j){
        const f32x4v v4 = ld[i*2+j];
        ushort4 hv;
        hv.x=f2bf(v4.x); hv.y=f2bf(v4.y); hv.z=f2bf(v4.z); hv.w=f2bf(v4.w);
        const int idx = (r*KC + l*8 + j*4) ^ ((r&7)<<3);
        *(ushort4*)&Ab[buf][idx] = hv;
      }
    }
  };
  auto loadB = [&](int c, bf16x8* bA, bf16x8* bB){
    const int v = c>>2;
    #pragma unroll
    for (int ks=0;ks<2;++ks){
      const int kl = w*64 + ks*32 + oc*8;
      const int kg8 = ((c&3)*KC + kl) >> 3;
      const unsigned short* fragBase = Wp + (((size_t)v*256 + kg8)*17)*8;
      bA[ks] = *(const bf16x8*)(fragBase + lo*8);
      bf16x8 z = {0,0,0,0,0,0,0,0};
      bB[ks] = (lo==0) ? *(const bf16x8*)(fragBase + 16*8) : z;
    }
  };

  issue(0); writeLDS(0);
  bf16x8 curA[2], curB[2], nxtA[2], nxtB[2];
  loadB(0, curA, curB);
  __syncthreads();

  const int swz = (lo&7)<<3;
  const int er = tid>>4, ec = tid&15;        // epilogue coords: er 0..31
  const int tile = er>>4, r16 = er&15;

  for (int c=0;c<NCH;++c){
    const int buf = c&1;
    if (c+1<NCH){ issue(c+1); loadB(c+1, nxtA, nxtB); }
    const int v = c>>2;
    #pragma unroll
    for (int ks=0;ks<2;++ks){
      const int kl = w*64 + ks*32 + oc*8;
      bf16x8 a0 = *(const bf16x8*)&Ab[buf][(lo*KC + kl) ^ swz];
      bf16x8 a1 = *(const bf16x8*)&Ab[buf][((16+lo)*KC + kl) ^ swz];
      acc00 = __builtin_amdgcn_mfma_f32_16x16x32_bf16(a0, curA[ks], acc00, 0,0,0);
      acc10 = __builtin_amdgcn_mfma_f32_16x16x32_bf16(a1, curA[ks], acc10, 0,0,0);
      acc01 = __builtin_amdgcn_mfma_f32_16x16x32_bf16(a0, curB[ks], acc01, 0,0,0);
      acc11 = __builtin_amdgcn_mfma_f32_16x16x32_bf16(a1, curB[ks], acc11, 0,0,0);
    }
    curA[0]=nxtA[0]; curA[1]=nxtA[1]; curB[0]=nxtB[0]; curB[1]=nxtB[1];

    if ((c&3)==3){
      // ---- single-pass cross-wave reduce + epilogue (all 32 rows at once)
      #pragma unroll
      for (int r=0;r<4;++r){
        const int ri = (oc*4+r)*16+lo;
        red[w][0][ri] = acc00[r];   // rows 0-15, cols 0-15
        red[w][1][ri] = acc10[r];   // rows 16-31, cols 0-15
        red[w][2][ri] = acc01[r];   // rows 0-15, col 16 (lane col 0)
        red[w][3][ri] = acc11[r];   // rows 16-31, col 16
      }
      acc00 = (f32x4){0.f,0.f,0.f,0.f};
      acc01 = (f32x4){0.f,0.f,0.f,0.f};
      acc10 = (f32x4){0.f,0.f,0.f,0.f};
      acc11 = (f32x4){0.f,0.f,0.f,0.f};
      __syncthreads();
      {
        const int ri = r16*16 + ec;
        float h0 = red[0][tile][ri]+red[1][tile][ri]+red[2][tile][ri]+red[3][tile][ri]
                 + red[4][tile][ri]+red[5][tile][ri]+red[6][tile][ri]+red[7][tile][ri]
                 + b0[v*J+ec];
        const int row = rowBase + er;
        C[(size_t)row*VO + v*J + ec] = f2bf(h0);
        float s0 = h0, q0 = h0*h0;
        float s1 = 0.f, q1 = 0.f;
        if (ec==0){
          const int r2 = r16*16;
          float h1 = red[0][2+tile][r2]+red[1][2+tile][r2]+red[2][2+tile][r2]+red[3][2+tile][r2]
                   + red[4][2+tile][r2]+red[5][2+tile][r2]+red[6][2+tile][r2]+red[7][2+tile][r2]
                   + b0[v*J+16];
          C[(size_t)row*VO + v*J + 16] = f2bf(h1);
          s1 = h1; q1 = h1*h1;
        }
        s0 += __shfl_xor(s0,16); s0 += __shfl_xor(s0,32);
        q0 += __shfl_xor(q0,16); q0 += __shfl_xor(q0,32);
        s1 += __shfl_xor(s1,16); s1 += __shfl_xor(s1,32);
        q1 += __shfl_xor(q1,16); q1 += __shfl_xor(q1,32);
        if (l < 16){ atomicAdd(&bS[v*J+l], s0); atomicAdd(&bQ[v*J+l], q0); }
        if (l == 0){ atomicAdd(&bS[v*J+16], s1); atomicAdd(&bQ[v*J+16], q1); }
      }
      __syncthreads();
    }
    if (c+1<NCH){
      writeLDS(buf^1);
      __syncthreads();
    }
  }

  __syncthreads();
  const int rep = blockIdx.x & 7;
  for (int i=tid;i<VO;i+=512){
    atomicAdd(&stat0[rep*512+i],        bS[i]);
    atomicAdd(&stat0[4096 + rep*512+i], bQ[i]);
  }
}

// -------- chain v4 (round-18 verbatim): bf16 activations, MFMA conv, prebuilt W frags
template<int RESID,int WRITEF,int CONV>
__global__ __launch_bounds__(256) void chain_kernel(
  const unsigned short* __restrict__ Cin, unsigned short* __restrict__ Cout,
  float* __restrict__ F, float* __restrict__ outF,
  const float* __restrict__ statJ,
  const float* __restrict__ g, const float* __restrict__ be,
  const unsigned short* __restrict__ wfA_g, const unsigned short* __restrict__ wfB_g,
  const float* __restrict__ bc,
  float* __restrict__ statN)
{
  __shared__ float aC[VO], cC[VO], bb[VO];
  __shared__ float ssum[VO], ssq[VO];
  __shared__ float hb1[4][4][J*JP];
  __shared__ __align__(16) unsigned short hb2[16*576];

  const int tid = threadIdx.x, wv = tid>>6, lane = tid&63;
  const int lo = lane&15, oc = lane>>4;
  const int rowBase = blockIdx.x*16;

  for (int i=tid;i<VO;i+=256){
    float s=0.f,q=0.f;
    #pragma unroll
    for (int r=0;r<8;++r){ s += statJ[r*512+i]; q += statJ[4096 + r*512+i]; }
    float mu  = s*(1.f/NB);
    float var = q*(1.f/NB) - mu*mu;
    float A = rsqrtf(var + EPSB)*g[i];
    aC[i]=A; cC[i]=be[i]-mu*A;
    ssum[i]=0.f; ssq[i]=0.f;
    if (CONV) bb[i]=bc[i];
  }
  if (CONV){
    for (int i=tid;i<16*576/8;i+=256) ((uint4*)hb2)[i] = (uint4){0,0,0,0};
  }
  __syncthreads();

  #pragma unroll
  for (int r4=0;r4<4;++r4){
    const int row = wv*4 + r4;
    const unsigned short* cr = Cin + (size_t)(rowBase+row)*VO;
    #pragma unroll
    for (int s=0;s<5;++s){
      int vo = lane + 64*s;
      if (vo<VO){ int vtx=vo/J, o=vo-vtx*J; hb1[wv][r4][vtx*JP+o] = bf2f(cr[vo])*aC[vo] + cC[vo]; }
    }
  }
  asm volatile("s_waitcnt lgkmcnt(0)" ::: "memory");
  #pragma unroll
  for (int r4=0;r4<4;++r4){
    const int row = wv*4 + r4;
    #pragma unroll
    for (int s=0;s<5;++s){
      int vo = lane + 64*s;
      if (vo<VO){
        int vtx=vo/J, o=vo-vtx*J;
        unsigned m = ADJM[vtx];
        float a = 0.f;
        while (m){ int u=__ffs(m)-1; m&=m-1; a += hb1[wv][r4][u*JP+o]; }
        a = a>0.f ? a : 0.f;
        size_t gi = (size_t)(rowBase+row)*VO + vo;
        if (RESID)  a += F[gi];
        if (WRITEF) F[gi] = a;
        if (CONV){
          int idx = (row*576 + vtx*32 + o) ^ ((row&7)<<3);
          hb2[idx] = f2bf(a);
        } else {
          outF[gi] = a;
        }
      }
    }
  }
  if (!CONV) return;
  __syncthreads();

  for (int v=wv; v<J; v+=4){
    const int aidx = (lo*576 + v*32 + oc*8) ^ ((lo&7)<<3);
    bf16x8 a  = *(const bf16x8*)&hb2[aidx];
    bf16x8 bA = *(const bf16x8*)(wfA_g + ((size_t)v*64 + lane)*8);
    bf16x8 bB = {0,0,0,0,0,0,0,0};
    if (lo==0) bB = *(const bf16x8*)(wfB_g + ((size_t)v*4 + oc)*8);
    f32x4 acc0 = (f32x4){0.f,0.f,0.f,0.f};
    f32x4 acc1 = (f32x4){0.f,0.f,0.f,0.f};
    acc0 = __builtin_amdgcn_mfma_f32_16x16x32_bf16(a, bA, acc0, 0,0,0);
    acc1 = __builtin_amdgcn_mfma_f32_16x16x32_bf16(a, bB, acc1, 0,0,0);

    const float bias0 = bb[v*J+lo];
    const float bias1 = bb[v*J+16];
    float s0=0.f,q0=0.f,s1=0.f,q1=0.f;
    #pragma unroll
    for (int r=0;r<4;++r){
      const int row = rowBase + oc*4 + r;
      const float h0 = acc0[r] + bias0;
      Cout[(size_t)row*VO + v*J + lo] = f2bf(h0);
      s0 += h0; q0 += h0*h0;
      if (lo==0){
        const float h1 = acc1[r] + bias1;
        Cout[(size_t)row*VO + v*J + 16] = f2bf(h1);
        s1 += h1; q1 += h1*h1;
      }
    }
    s0 += __shfl_xor(s0,16); s0 += __shfl_xor(s0,32);
    q0 += __shfl_xor(q0,16); q0 += __shfl_xor(q0,32);
    s1 += __shfl_xor(s1,16); s1 += __shfl_xor(s1,32);
    q1 += __shfl_xor(q1,16); q1 += __shfl_xor(q1,32);
    if (lane < 16){ atomicAdd(&ssum[v*J+lo], s0); atomicAdd(&ssq[v*J+lo], q0); }
    if (lane == 0){ atomicAdd(&ssum[v*J+16], s1); atomicAdd(&ssq[v*J+16], q1); }
  }
  __syncthreads();
  const int rep = blockIdx.x & 7;
  for (int i=tid;i<VO;i+=256){
    atomicAdd(&statN[rep*512+i],        ssum[i]);
    atomicAdd(&statN[4096 + rep*512+i], ssq[i]);
  }
}

extern "C" void kernel_launch(void* const* d_in, const int* in_sizes, int n_in,
                              void* d_out, int out_size, void* d_ws, size_t ws_size,
                              hipStream_t stream)
{
  (void)in_sizes; (void)n_in; (void)out_size; (void)ws_size;
  const float* img = (const float*)d_in[0];
  const float* W0  = (const float*)d_in[1];
  const float* b0  = (const float*)d_in[2];
  const float* g0  = (const float*)d_in[3];
  const float* be0 = (const float*)d_in[4];
  const float* Wr  = (const float*)d_in[5];
  const float* br  = (const float*)d_in[6];
  const float* gr  = (const float*)d_in[7];
  const float* ber = (const float*)d_in[8];

  float* ws = (float*)d_ws;
  float* ST = ws;                                        // 73728 floats
  unsigned short* Wp  = (unsigned short*)(ws + 73728);   // 591872 ush (300000 f reserved)
  unsigned short* WfA = (unsigned short*)(ws + 73728 + 300000);   // 69632 ush
  unsigned short* WfB = WfA + 8*17*64*8;                          //  4352 ush (40000 f reserved)
  unsigned short* Ca = (unsigned short*)(ws + 73728 + 300000 + 40000);   // NB*VO ush
  unsigned short* Cb = Ca + (size_t)NB*VO;                               // NB*VO ush
  float* F  = ws + 73728 + 300000 + 40000 + (size_t)NB*VO;               // NB*VO f32
  float* out = (float*)d_out;

  zero_stats<<<72,256,0,stream>>>(ST, 9*8192);
  wconv_kernel<<<136,256,0,stream>>>(W0, Wp);
  wfrag_kernel<<<34,256,0,stream>>>(Wr, WfA, WfB);

  conv0_kernel<<<256,512,0,stream>>>(img, Wp, b0, Ca, ST);

  #define STG(j) (ST + (j)*8192)
  #define WFA(s) (WfA + (size_t)(s)*17*64*8)
  #define WFB(s) (WfB + (size_t)(s)*17*4*8)
  chain_kernel<0,1,1><<<512,256,0,stream>>>(Ca, Cb, F, nullptr, STG(0), g0,      be0,
                                            WFA(0), WFB(0), br+0*VO, STG(1));
  chain_kernel<0,0,1><<<512,256,0,stream>>>(Cb, Ca, F, nullptr, STG(1), gr+0*VO, ber+0*VO,
                                            WFA(1), WFB(1), br+1*VO, STG(2));
  chain_kernel<1,1,1><<<512,256,0,stream>>>(Ca, Cb, F, nullptr, STG(2), gr+1*VO, ber+1*VO,
                                            WFA(2), WFB(2), br+2*VO, STG(3));
  chain_kernel<0,0,1><<<512,256,0,stream>>>(Cb, Ca, F, nullptr, STG(3), gr+2*VO, ber+2*VO,
                                            WFA(3), WFB(3), br+3*VO, STG(4));
  chain_kernel<1,1,1><<<512,256,0,stream>>>(Ca, Cb, F, nullptr, STG(4), gr+3*VO, ber+3*VO,
                                            WFA(4), WFB(4), br+4*VO, STG(5));
  chain_kernel<0,0,1><<<512,256,0,stream>>>(Cb, Ca, F, nullptr, STG(5), gr+4*VO, ber+4*VO,
                                            WFA(5), WFB(5), br+5*VO, STG(6));
  chain_kernel<1,1,1><<<512,256,0,stream>>>(Ca, Cb, F, nullptr, STG(6), gr+5*VO, ber+5*VO,
                                            WFA(6), WFB(6), br+6*VO, STG(7));
  chain_kernel<0,0,1><<<512,256,0,stream>>>(Cb, Ca, F, nullptr, STG(7), gr+6*VO, ber+6*VO,
                                            WFA(7), WFB(7), br+7*VO, STG(8));
  chain_kernel<1,0,0><<<512,256,0,stream>>>(Ca, nullptr, F, out, STG(8), gr+7*VO, ber+7*VO,
                                            nullptr, nullptr, nullptr, nullptr);
  #undef STG
  #undef WFA
  #undef WFB
}

// Round 21
// 452.495 us; speedup vs baseline: 1.0005x; 1.0005x over previous
//
#include <hip/hip_runtime.h>

#define J 17
#define JP 18
#define VO 289            // 17*17
#define NB 8192
#define DIN 2048
#define EPSB 1e-5f
#define KC 512            // conv0: k-floats per staged chunk (2KB per row)
#define RT 32             // conv0: rows per block
#define NCH 68            // 17*2048/512 chunks per row

typedef __attribute__((ext_vector_type(8))) short bf16x8;
typedef __attribute__((ext_vector_type(4))) float f32x4;
typedef __attribute__((ext_vector_type(4))) float f32x4v;

// adjacency (incl. self) as bitmasks, from SKEL
__device__ __constant__ unsigned ADJM[J] = {
  0x7u, 0xFu, 0x17u, 0x2Au, 0x54u, 0x8E8u, 0x1170u, 0x2A0u, 0x540u,
  0x280u, 0x500u, 0x3820u, 0x5840u, 0xA800u, 0x15000u, 0xA000u, 0x14000u};

__device__ inline unsigned short f2bf(float x){
  unsigned u = __float_as_uint(x);
  return (unsigned short)((u + 0x7fffu + ((u>>16)&1u)) >> 16);   // RNE
}
__device__ inline float bf2f(unsigned short u){
  return __uint_as_float(((unsigned)u)<<16);
}

__global__ void zero_stats(float* p, int n) {
  int i = blockIdx.x*blockDim.x + threadIdx.x;
  int stride = gridDim.x*blockDim.x;
  for (; i < n; i += stride) p[i] = 0.f;
}

// -------- prepass: W0 -> Wp fragment-major [v][k/8][col 0..16][8]
__global__ __launch_bounds__(256) void wconv_kernel(
    const float* __restrict__ W0, unsigned short* __restrict__ Wp)
{
  int t = blockIdx.x*256 + threadIdx.x;
  int v = t >> 11, k = t & 2047;
  const float* src = W0 + (size_t)t*J;
  unsigned short* dst = Wp + (((size_t)v*256 + (k>>3))*17)*8 + (k&7);
  #pragma unroll
  for (int o=0;o<J;++o)  dst[o*8] = f2bf(src[o]);
}

// -------- prepass: chain W fragments for ALL 8 stages (MFMA B layout)
__global__ __launch_bounds__(256) void wfrag_kernel(
    const float* __restrict__ Wr, unsigned short* __restrict__ WfA,
    unsigned short* __restrict__ WfB)
{
  int t = blockIdx.x*256 + threadIdx.x;
  if (t < 8*17*64) {
    int s = t/(17*64), rem = t - s*17*64, v = rem>>6, ll = rem&63;
    int c = ll&15, o8 = ll>>4;
    unsigned short* dst = WfA + (size_t)t*8;
    const float* w = Wr + ((size_t)(s*J + v)*J)*J;
    #pragma unroll
    for (int j=0;j<8;++j){ int d=o8*8+j; dst[j] = (d<J) ? f2bf(w[(size_t)d*J + c]) : (unsigned short)0; }
  }
  if (t < 8*17*4) {
    int s = t/(17*4), rem = t - s*17*4, v = rem>>2, o8 = rem&3;
    unsigned short* dst = WfB + (size_t)t*8;
    const float* w = Wr + ((size_t)(s*J + v)*J)*J;
    #pragma unroll
    for (int j=0;j<8;++j){ int d=o8*8+j; dst[j] = (d<J) ? f2bf(w[(size_t)d*J + 16]) : (unsigned short)0; }
  }
}

// -------- conv0 v9: wave-owns-4-rows staging (1KB contiguous bursts, 2048 streams)
// + B register prefetch + single-pass epilogue (r19 otherwise)
__global__ __launch_bounds__(512) void conv0_kernel(
    const float* __restrict__ feat, const unsigned short* __restrict__ Wp,
    const float* __restrict__ b0, unsigned short* __restrict__ C,
    float* __restrict__ stat0)
{
  const int tid = threadIdx.x, w = tid>>6, l = tid&63;
  const int lo = l&15, oc = l>>4;
  const int rowBase = blockIdx.x*RT;

  __shared__ __align__(16) unsigned short Ab[2][RT*KC];   // 64 KB
  __shared__ float red[8][4][256];                        // 32 KB single-pass reduce
  __shared__ float bS[VO], bQ[VO];

  for (int i=tid;i<VO;i+=512){ bS[i]=0.f; bQ[i]=0.f; }

  f32x4 acc00 = (f32x4){0.f,0.f,0.f,0.f};
  f32x4 acc01 = (f32x4){0.f,0.f,0.f,0.f};
  f32x4 acc10 = (f32x4){0.f,0.f,0.f,0.f};
  f32x4 acc11 = (f32x4){0.f,0.f,0.f,0.f};

  const float* fbase = feat + (size_t)rowBase*(J*DIN);
  f32x4v ld[8];

  // wave w owns rows 4w..4w+3; lane l covers floats [l*8, l*8+8) of each row's 2KB chunk
  auto issue = [&](int c){
    #pragma unroll
    for (int i=0;i<4;++i){
      const float* src = fbase + (size_t)(w*4+i)*(J*DIN) + c*KC + l*8;
      ld[i*2+0] = __builtin_nontemporal_load((const f32x4v*)src);
      ld[i*2+1] = __builtin_nontemporal_load((const f32x4v*)src + 1);
    }
  };
  auto writeLDS = [&](int buf){
    #pragma unroll
    for (int i=0;i<4;++i){
      const int r = w*4 + i;
      #pragma unroll
      for (int j=0;j<2;++j){
        const f32x4v v4 = ld[i*2+j];
        ushort4 hv;
        hv.x=f2bf(v4.x); hv.y=f2bf(v4.y); hv.z=f2bf(v4.z); hv.w=f2bf(v4.w);
        const int idx = (r*KC + l*8 + j*4) ^ ((r&7)<<3);
        *(ushort4*)&Ab[buf][idx] = hv;
      }
    }
  };
  auto loadB = [&](int c, bf16x8* bA, bf16x8* bB){
    const int v = c>>2;
    #pragma unroll
    for (int ks=0;ks<2;++ks){
      const int kl = w*64 + ks*32 + oc*8;
      const int kg8 = ((c&3)*KC + kl) >> 3;
      const unsigned short* fragBase = Wp + (((size_t)v*256 + kg8)*17)*8;
      bA[ks] = *(const bf16x8*)(fragBase + lo*8);
      bf16x8 z = {0,0,0,0,0,0,0,0};
      bB[ks] = (lo==0) ? *(const bf16x8*)(fragBase + 16*8) : z;
    }
  };

  issue(0); writeLDS(0);
  bf16x8 curA[2], curB[2], nxtA[2], nxtB[2];
  loadB(0, curA, curB);
  __syncthreads();

  const int swz = (lo&7)<<3;
  const int er = tid>>4, ec = tid&15;        // epilogue coords: er 0..31
  const int tile = er>>4, r16 = er&15;

  for (int c=0;c<NCH;++c){
    const int buf = c&1;
    if (c+1<NCH){ issue(c+1); loadB(c+1, nxtA, nxtB); }
    const int v = c>>2;
    #pragma unroll
    for (int ks=0;ks<2;++ks){
      const int kl = w*64 + ks*32 + oc*8;
      bf16x8 a0 = *(const bf16x8*)&Ab[buf][(lo*KC + kl) ^ swz];
      bf16x8 a1 = *(const bf16x8*)&Ab[buf][((16+lo)*KC + kl) ^ swz];
      acc00 = __builtin_amdgcn_mfma_f32_16x16x32_bf16(a0, curA[ks], acc00, 0,0,0);
      acc10 = __builtin_amdgcn_mfma_f32_16x16x32_bf16(a1, curA[ks], acc10, 0,0,0);
      acc01 = __builtin_amdgcn_mfma_f32_16x16x32_bf16(a0, curB[ks], acc01, 0,0,0);
      acc11 = __builtin_amdgcn_mfma_f32_16x16x32_bf16(a1, curB[ks], acc11, 0,0,0);
    }
    curA[0]=nxtA[0]; curA[1]=nxtA[1]; curB[0]=nxtB[0]; curB[1]=nxtB[1];

    if ((c&3)==3){
      // ---- single-pass cross-wave reduce + epilogue (all 32 rows at once)
      #pragma unroll
      for (int r=0;r<4;++r){
        const int ri = (oc*4+r)*16+lo;
        red[w][0][ri] = acc00[r];   // rows 0-15, cols 0-15
        red[w][1][ri] = acc10[r];   // rows 16-31, cols 0-15
        red[w][2][ri] = acc01[r];   // rows 0-15, col 16 (lane col 0)
        red[w][3][ri] = acc11[r];   // rows 16-31, col 16
      }
      acc00 = (f32x4){0.f,0.f,0.f,0.f};
      acc01 = (f32x4){0.f,0.f,0.f,0.f};
      acc10 = (f32x4){0.f,0.f,0.f,0.f};
      acc11 = (f32x4){0.f,0.f,0.f,0.f};
      __syncthreads();
      {
        const int ri = r16*16 + ec;
        float h0 = red[0][tile][ri]+red[1][tile][ri]+red[2][tile][ri]+red[3][tile][ri]
                 + red[4][tile][ri]+red[5][tile][ri]+red[6][tile][ri]+red[7][tile][ri]
                 + b0[v*J+ec];
        const int row = rowBase + er;
        C[(size_t)row*VO + v*J + ec] = f2bf(h0);
        float s0 = h0, q0 = h0*h0;
        float s1 = 0.f, q1 = 0.f;
        if (ec==0){
          const int r2 = r16*16;
          float h1 = red[0][2+tile][r2]+red[1][2+tile][r2]+red[2][2+tile][r2]+red[3][2+tile][r2]
                   + red[4][2+tile][r2]+red[5][2+tile][r2]+red[6][2+tile][r2]+red[7][2+tile][r2]
                   + b0[v*J+16];
          C[(size_t)row*VO + v*J + 16] = f2bf(h1);
          s1 = h1; q1 = h1*h1;
        }
        s0 += __shfl_xor(s0,16); s0 += __shfl_xor(s0,32);
        q0 += __shfl_xor(q0,16); q0 += __shfl_xor(q0,32);
        s1 += __shfl_xor(s1,16); s1 += __shfl_xor(s1,32);
        q1 += __shfl_xor(q1,16); q1 += __shfl_xor(q1,32);
        if (l < 16){ atomicAdd(&bS[v*J+l], s0); atomicAdd(&bQ[v*J+l], q0); }
        if (l == 0){ atomicAdd(&bS[v*J+16], s1); atomicAdd(&bQ[v*J+16], q1); }
      }
      __syncthreads();
    }
    if (c+1<NCH){
      writeLDS(buf^1);
      __syncthreads();
    }
  }

  __syncthreads();
  const int rep = blockIdx.x & 7;
  for (int i=tid;i<VO;i+=512){
    atomicAdd(&stat0[rep*512+i],        bS[i]);
    atomicAdd(&stat0[4096 + rep*512+i], bQ[i]);
  }
}

// -------- chain v4 (round-18 verbatim): bf16 activations, MFMA conv, prebuilt W frags
template<int RESID,int WRITEF,int CONV>
__global__ __launch_bounds__(256) void chain_kernel(
  const unsigned short* __restrict__ Cin, unsigned short* __restrict__ Cout,
  float* __restrict__ F, float* __restrict__ outF,
  const float* __restrict__ statJ,
  const float* __restrict__ g, const float* __restrict__ be,
  const unsigned short* __restrict__ wfA_g, const unsigned short* __restrict__ wfB_g,
  const float* __restrict__ bc,
  float* __restrict__ statN)
{
  __shared__ float aC[VO], cC[VO], bb[VO];
  __shared__ float ssum[VO], ssq[VO];
  __shared__ float hb1[4][4][J*JP];
  __shared__ __align__(16) unsigned short hb2[16*576];

  const int tid = threadIdx.x, wv = tid>>6, lane = tid&63;
  const int lo = lane&15, oc = lane>>4;
  const int rowBase = blockIdx.x*16;

  for (int i=tid;i<VO;i+=256){
    float s=0.f,q=0.f;
    #pragma unroll
    for (int r=0;r<8;++r){ s += statJ[r*512+i]; q += statJ[4096 + r*512+i]; }
    float mu  = s*(1.f/NB);
    float var = q*(1.f/NB) - mu*mu;
    float A = rsqrtf(var + EPSB)*g[i];
    aC[i]=A; cC[i]=be[i]-mu*A;
    ssum[i]=0.f; ssq[i]=0.f;
    if (CONV) bb[i]=bc[i];
  }
  if (CONV){
    for (int i=tid;i<16*576/8;i+=256) ((uint4*)hb2)[i] = (uint4){0,0,0,0};
  }
  __syncthreads();

  #pragma unroll
  for (int r4=0;r4<4;++r4){
    const int row = wv*4 + r4;
    const unsigned short* cr = Cin + (size_t)(rowBase+row)*VO;
    #pragma unroll
    for (int s=0;s<5;++s){
      int vo = lane + 64*s;
      if (vo<VO){ int vtx=vo/J, o=vo-vtx*J; hb1[wv][r4][vtx*JP+o] = bf2f(cr[vo])*aC[vo] + cC[vo]; }
    }
  }
  asm volatile("s_waitcnt lgkmcnt(0)" ::: "memory");
  #pragma unroll
  for (int r4=0;r4<4;++r4){
    const int row = wv*4 + r4;
    #pragma unroll
    for (int s=0;s<5;++s){
      int vo = lane + 64*s;
      if (vo<VO){
        int vtx=vo/J, o=vo-vtx*J;
        unsigned m = ADJM[vtx];
        float a = 0.f;
        while (m){ int u=__ffs(m)-1; m&=m-1; a += hb1[wv][r4][u*JP+o]; }
        a = a>0.f ? a : 0.f;
        size_t gi = (size_t)(rowBase+row)*VO + vo;
        if (RESID)  a += F[gi];
        if (WRITEF) F[gi] = a;
        if (CONV){
          int idx = (row*576 + vtx*32 + o) ^ ((row&7)<<3);
          hb2[idx] = f2bf(a);
        } else {
          outF[gi] = a;
        }
      }
    }
  }
  if (!CONV) return;
  __syncthreads();

  for (int v=wv; v<J; v+=4){
    const int aidx = (lo*576 + v*32 + oc*8) ^ ((lo&7)<<3);
    bf16x8 a  = *(const bf16x8*)&hb2[aidx];
    bf16x8 bA = *(const bf16x8*)(wfA_g + ((size_t)v*64 + lane)*8);
    bf16x8 bB = {0,0,0,0,0,0,0,0};
    if (lo==0) bB = *(const bf16x8*)(wfB_g + ((size_t)v*4 + oc)*8);
    f32x4 acc0 = (f32x4){0.f,0.f,0.f,0.f};
    f32x4 acc1 = (f32x4){0.f,0.f,0.f,0.f};
    acc0 = __builtin_amdgcn_mfma_f32_16x16x32_bf16(a, bA, acc0, 0,0,0);
    acc1 = __builtin_amdgcn_mfma_f32_16x16x32_bf16(a, bB, acc1, 0,0,0);

    const float bias0 = bb[v*J+lo];
    const float bias1 = bb[v*J+16];
    float s0=0.f,q0=0.f,s1=0.f,q1=0.f;
    #pragma unroll
    for (int r=0;r<4;++r){
      const int row = rowBase + oc*4 + r;
      const float h0 = acc0[r] + bias0;
      Cout[(size_t)row*VO + v*J + lo] = f2bf(h0);
      s0 += h0; q0 += h0*h0;
      if (lo==0){
        const float h1 = acc1[r] + bias1;
        Cout[(size_t)row*VO + v*J + 16] = f2bf(h1);
        s1 += h1; q1 += h1*h1;
      }
    }
    s0 += __shfl_xor(s0,16); s0 += __shfl_xor(s0,32);
    q0 += __shfl_xor(q0,16); q0 += __shfl_xor(q0,32);
    s1 += __shfl_xor(s1,16); s1 += __shfl_xor(s1,32);
    q1 += __shfl_xor(q1,16); q1 += __shfl_xor(q1,32);
    if (lane < 16){ atomicAdd(&ssum[v*J+lo], s0); atomicAdd(&ssq[v*J+lo], q0); }
    if (lane == 0){ atomicAdd(&ssum[v*J+16], s1); atomicAdd(&ssq[v*J+16], q1); }
  }
  __syncthreads();
  const int rep = blockIdx.x & 7;
  for (int i=tid;i<VO;i+=256){
    atomicAdd(&statN[rep*512+i],        ssum[i]);
    atomicAdd(&statN[4096 + rep*512+i], ssq[i]);
  }
}

extern "C" void kernel_launch(void* const* d_in, const int* in_sizes, int n_in,
                              void* d_out, int out_size, void* d_ws, size_t ws_size,
                              hipStream_t stream)
{
  (void)in_sizes; (void)n_in; (void)out_size; (void)ws_size;
  const float* img = (const float*)d_in[0];
  const float* W0  = (const float*)d_in[1];
  const float* b0  = (const float*)d_in[2];
  const float* g0  = (const float*)d_in[3];
  const float* be0 = (const float*)d_in[4];
  const float* Wr  = (const float*)d_in[5];
  const float* br  = (const float*)d_in[6];
  const float* gr  = (const float*)d_in[7];
  const float* ber = (const float*)d_in[8];

  float* ws = (float*)d_ws;
  float* ST = ws;                                        // 73728 floats
  unsigned short* Wp  = (unsigned short*)(ws + 73728);   // 591872 ush (300000 f reserved)
  unsigned short* WfA = (unsigned short*)(ws + 73728 + 300000);   // 69632 ush
  unsigned short* WfB = WfA + 8*17*64*8;                          //  4352 ush (40000 f reserved)
  unsigned short* Ca = (unsigned short*)(ws + 73728 + 300000 + 40000);   // NB*VO ush
  unsigned short* Cb = Ca + (size_t)NB*VO;                               // NB*VO ush
  float* F  = ws + 73728 + 300000 + 40000 + (size_t)NB*VO;               // NB*VO f32
  float* out = (float*)d_out;

  zero_stats<<<72,256,0,stream>>>(ST, 9*8192);
  wconv_kernel<<<136,256,0,stream>>>(W0, Wp);
  wfrag_kernel<<<34,256,0,stream>>>(Wr, WfA, WfB);

  conv0_kernel<<<256,512,0,stream>>>(img, Wp, b0, Ca, ST);

  #define STG(j) (ST + (j)*8192)
  #define WFA(s) (WfA + (size_t)(s)*17*64*8)
  #define WFB(s) (WfB + (size_t)(s)*17*4*8)
  chain_kernel<0,1,1><<<512,256,0,stream>>>(Ca, Cb, F, nullptr, STG(0), g0,      be0,
                                            WFA(0), WFB(0), br+0*VO, STG(1));
  chain_kernel<0,0,1><<<512,256,0,stream>>>(Cb, Ca, F, nullptr, STG(1), gr+0*VO, ber+0*VO,
                                            WFA(1), WFB(1), br+1*VO, STG(2));
  chain_kernel<1,1,1><<<512,256,0,stream>>>(Ca, Cb, F, nullptr, STG(2), gr+1*VO, ber+1*VO,
                                            WFA(2), WFB(2), br+2*VO, STG(3));
  chain_kernel<0,0,1><<<512,256,0,stream>>>(Cb, Ca, F, nullptr, STG(3), gr+2*VO, ber+2*VO,
                                            WFA(3), WFB(3), br+3*VO, STG(4));
  chain_kernel<1,1,1><<<512,256,0,stream>>>(Ca, Cb, F, nullptr, STG(4), gr+3*VO, ber+3*VO,
                                            WFA(4), WFB(4), br+4*VO, STG(5));
  chain_kernel<0,0,1><<<512,256,0,stream>>>(Cb, Ca, F, nullptr, STG(5), gr+4*VO, ber+4*VO,
                                            WFA(5), WFB(5), br+5*VO, STG(6));
  chain_kernel<1,1,1><<<512,256,0,stream>>>(Ca, Cb, F, nullptr, STG(6), gr+5*VO, ber+5*VO,
                                            WFA(6), WFB(6), br+6*VO, STG(7));
  chain_kernel<0,0,1><<<512,256,0,stream>>>(Cb, Ca, F, nullptr, STG(7), gr+6*VO, ber+6*VO,
                                            WFA(7), WFB(7), br+7*VO, STG(8));
  chain_kernel<1,0,0><<<512,256,0,stream>>>(Ca, nullptr, F, out, STG(8), gr+7*VO, ber+7*VO,
                                            nullptr, nullptr, nullptr, nullptr);
  #undef STG
  #undef WFA
  #undef WFB
}

// Round 22
// 396.381 us; speedup vs baseline: 1.1421x; 1.1416x over previous
//
#include <hip/hip_runtime.h>

#define J 17
#define JP 18
#define VO 289            // 17*17
#define NB 8192
#define DIN 2048
#define EPSB 1e-5f
#define KC 512            // conv0: k-floats per staged chunk (2KB per row)
#define RT 32             // conv0: rows per block
#define NCH 68            // 17*2048/512 chunks per row

typedef __attribute__((ext_vector_type(8))) short bf16x8;
typedef __attribute__((ext_vector_type(4))) float f32x4;
typedef __attribute__((ext_vector_type(4))) float f32x4v;

// adjacency (incl. self) as bitmasks, from SKEL
__device__ __constant__ unsigned ADJM[J] = {
  0x7u, 0xFu, 0x17u, 0x2Au, 0x54u, 0x8E8u, 0x1170u, 0x2A0u, 0x540u,
  0x280u, 0x500u, 0x3820u, 0x5840u, 0xA800u, 0x15000u, 0xA000u, 0x14000u};

__device__ inline unsigned short f2bf(float x){
  unsigned u = __float_as_uint(x);
  return (unsigned short)((u + 0x7fffu + ((u>>16)&1u)) >> 16);   // RNE
}
__device__ inline float bf2f(unsigned short u){
  return __uint_as_float(((unsigned)u)<<16);
}

__global__ void zero_stats(float* p, int n) {
  int i = blockIdx.x*blockDim.x + threadIdx.x;
  int stride = gridDim.x*blockDim.x;
  for (; i < n; i += stride) p[i] = 0.f;
}

// -------- prepass: W0 -> Wp fragment-major [v][k/8][col 0..16][8]
__global__ __launch_bounds__(256) void wconv_kernel(
    const float* __restrict__ W0, unsigned short* __restrict__ Wp)
{
  int t = blockIdx.x*256 + threadIdx.x;
  int v = t >> 11, k = t & 2047;
  const float* src = W0 + (size_t)t*J;
  unsigned short* dst = Wp + (((size_t)v*256 + (k>>3))*17)*8 + (k&7);
  #pragma unroll
  for (int o=0;o<J;++o)  dst[o*8] = f2bf(src[o]);
}

// -------- prepass: chain W fragments for ALL 8 stages (MFMA B layout)
__global__ __launch_bounds__(256) void wfrag_kernel(
    const float* __restrict__ Wr, unsigned short* __restrict__ WfA,
    unsigned short* __restrict__ WfB)
{
  int t = blockIdx.x*256 + threadIdx.x;
  if (t < 8*17*64) {
    int s = t/(17*64), rem = t - s*17*64, v = rem>>6, ll = rem&63;
    int c = ll&15, o8 = ll>>4;
    unsigned short* dst = WfA + (size_t)t*8;
    const float* w = Wr + ((size_t)(s*J + v)*J)*J;
    #pragma unroll
    for (int j=0;j<8;++j){ int d=o8*8+j; dst[j] = (d<J) ? f2bf(w[(size_t)d*J + c]) : (unsigned short)0; }
  }
  if (t < 8*17*4) {
    int s = t/(17*4), rem = t - s*17*4, v = rem>>2, o8 = rem&3;
    unsigned short* dst = WfB + (size_t)t*8;
    const float* w = Wr + ((size_t)(s*J + v)*J)*J;
    #pragma unroll
    for (int j=0;j<8;++j){ int d=o8*8+j; dst[j] = (d<J) ? f2bf(w[(size_t)d*J + 16]) : (unsigned short)0; }
  }
}

// -------- conv0 v7: round-13 structure, C written as bf16  [r18 verbatim]
__global__ __launch_bounds__(512) void conv0_kernel(
    const float* __restrict__ feat, const unsigned short* __restrict__ Wp,
    const float* __restrict__ b0, unsigned short* __restrict__ C,
    float* __restrict__ stat0)
{
  const int tid = threadIdx.x, w = tid>>6, l = tid&63;
  const int lo = l&15, oc = l>>4;
  const int sr = tid>>4, sc = tid&15;
  const int rowBase = blockIdx.x*RT;

  __shared__ __align__(16) unsigned short Ab[2][RT*KC];
  __shared__ float red[8][2][256];
  __shared__ float bS[VO], bQ[VO];

  for (int i=tid;i<VO;i+=512){ bS[i]=0.f; bQ[i]=0.f; }

  f32x4 acc00 = (f32x4){0.f,0.f,0.f,0.f};
  f32x4 acc01 = (f32x4){0.f,0.f,0.f,0.f};
  f32x4 acc10 = (f32x4){0.f,0.f,0.f,0.f};
  f32x4 acc11 = (f32x4){0.f,0.f,0.f,0.f};

  const float* frow = feat + (size_t)(rowBase + sr)*(J*DIN);
  f32x4v ld[8];

  auto issue = [&](int c){
    const f32x4v* src = (const f32x4v*)(frow + c*KC + sc*4);
    #pragma unroll
    for (int i=0;i<8;++i) ld[i] = __builtin_nontemporal_load(src + i*16);
  };
  auto writeLDS = [&](int buf){
    #pragma unroll
    for (int i=0;i<8;++i){
      ushort4 hv;
      hv.x=f2bf(ld[i].x); hv.y=f2bf(ld[i].y); hv.z=f2bf(ld[i].z); hv.w=f2bf(ld[i].w);
      const int f = sc*4 + i*64;
      *(ushort4*)&Ab[buf][(sr*KC + f) ^ ((sr&7)<<3)] = hv;
    }
  };

  issue(0); writeLDS(0);
  __syncthreads();

  const int swz = (lo&7)<<3;

  for (int c=0;c<NCH;++c){
    const int buf = c&1;
    if (c+1<NCH) issue(c+1);
    const int v = c>>2;
    #pragma unroll
    for (int ks=0;ks<2;++ks){
      const int kl = w*64 + ks*32 + oc*8;
      bf16x8 a0 = *(const bf16x8*)&Ab[buf][(lo*KC + kl) ^ swz];
      bf16x8 a1 = *(const bf16x8*)&Ab[buf][((16+lo)*KC + kl) ^ swz];
      const int kg8 = ((c&3)*KC + kl) >> 3;
      const unsigned short* fragBase = Wp + (((size_t)v*256 + kg8)*17)*8;
      bf16x8 bA = *(const bf16x8*)(fragBase + lo*8);
      bf16x8 bB = {0,0,0,0,0,0,0,0};
      if (lo==0) bB = *(const bf16x8*)(fragBase + 16*8);
      acc00 = __builtin_amdgcn_mfma_f32_16x16x32_bf16(a0, bA, acc00, 0,0,0);
      acc10 = __builtin_amdgcn_mfma_f32_16x16x32_bf16(a1, bA, acc10, 0,0,0);
      acc01 = __builtin_amdgcn_mfma_f32_16x16x32_bf16(a0, bB, acc01, 0,0,0);
      acc11 = __builtin_amdgcn_mfma_f32_16x16x32_bf16(a1, bB, acc11, 0,0,0);
    }
    if ((c&3)==3){
      #pragma unroll
      for (int pass=0; pass<2; ++pass){
        #pragma unroll
        for (int r=0;r<4;++r){
          red[w][0][(oc*4+r)*16+lo] = pass ? acc10[r] : acc00[r];
          red[w][1][(oc*4+r)*16+lo] = pass ? acc11[r] : acc01[r];
        }
        __syncthreads();
        if (tid < 256){
          const int er = tid>>4, ec = tid&15;
          const int ri = er*16+ec;
          float h0 = red[0][0][ri]+red[1][0][ri]+red[2][0][ri]+red[3][0][ri]
                   + red[4][0][ri]+red[5][0][ri]+red[6][0][ri]+red[7][0][ri]
                   + b0[v*J+ec];
          const int row = rowBase + pass*16 + er;
          C[(size_t)row*VO + v*J + ec] = f2bf(h0);
          float s0 = h0, q0 = h0*h0;
          float s1 = 0.f, q1 = 0.f;
          if (ec==0){
            const int r2 = er*16;
            float h1 = red[0][1][r2]+red[1][1][r2]+red[2][1][r2]+red[3][1][r2]
                     + red[4][1][r2]+red[5][1][r2]+red[6][1][r2]+red[7][1][r2]
                     + b0[v*J+16];
            C[(size_t)row*VO + v*J + 16] = f2bf(h1);
            s1 = h1; q1 = h1*h1;
          }
          s0 += __shfl_xor(s0,16); s0 += __shfl_xor(s0,32);
          q0 += __shfl_xor(q0,16); q0 += __shfl_xor(q0,32);
          s1 += __shfl_xor(s1,16); s1 += __shfl_xor(s1,32);
          q1 += __shfl_xor(q1,16); q1 += __shfl_xor(q1,32);
          if (l < 16){ atomicAdd(&bS[v*J+l], s0); atomicAdd(&bQ[v*J+l], q0); }
          if (l == 0){ atomicAdd(&bS[v*J+16], s1); atomicAdd(&bQ[v*J+16], q1); }
        }
        __syncthreads();
      }
      acc00 = (f32x4){0.f,0.f,0.f,0.f};
      acc01 = (f32x4){0.f,0.f,0.f,0.f};
      acc10 = (f32x4){0.f,0.f,0.f,0.f};
      acc11 = (f32x4){0.f,0.f,0.f,0.f};
    }
    if (c+1<NCH){
      writeLDS(buf^1);
      __syncthreads();
    }
  }

  __syncthreads();
  const int rep = blockIdx.x & 7;
  for (int i=tid;i<VO;i+=512){
    atomicAdd(&stat0[rep*512+i],        bS[i]);
    atomicAdd(&stat0[4096 + rep*512+i], bQ[i]);
  }
}

// -------- chain v4 (r18 verbatim): bf16 activations, MFMA conv, prebuilt W frags
template<int RESID,int WRITEF,int CONV>
__global__ __launch_bounds__(256) void chain_kernel(
  const unsigned short* __restrict__ Cin, unsigned short* __restrict__ Cout,
  float* __restrict__ F, float* __restrict__ outF,
  const float* __restrict__ statJ,
  const float* __restrict__ g, const float* __restrict__ be,
  const unsigned short* __restrict__ wfA_g, const unsigned short* __restrict__ wfB_g,
  const float* __restrict__ bc,
  float* __restrict__ statN)
{
  __shared__ float aC[VO], cC[VO], bb[VO];
  __shared__ float ssum[VO], ssq[VO];
  __shared__ float hb1[4][4][J*JP];
  __shared__ __align__(16) unsigned short hb2[16*576];

  const int tid = threadIdx.x, wv = tid>>6, lane = tid&63;
  const int lo = lane&15, oc = lane>>4;
  const int rowBase = blockIdx.x*16;

  for (int i=tid;i<VO;i+=256){
    float s=0.f,q=0.f;
    #pragma unroll
    for (int r=0;r<8;++r){ s += statJ[r*512+i]; q += statJ[4096 + r*512+i]; }
    float mu  = s*(1.f/NB);
    float var = q*(1.f/NB) - mu*mu;
    float A = rsqrtf(var + EPSB)*g[i];
    aC[i]=A; cC[i]=be[i]-mu*A;
    ssum[i]=0.f; ssq[i]=0.f;
    if (CONV) bb[i]=bc[i];
  }
  if (CONV){
    for (int i=tid;i<16*576/8;i+=256) ((uint4*)hb2)[i] = (uint4){0,0,0,0};
  }
  __syncthreads();

  #pragma unroll
  for (int r4=0;r4<4;++r4){
    const int row = wv*4 + r4;
    const unsigned short* cr = Cin + (size_t)(rowBase+row)*VO;
    #pragma unroll
    for (int s=0;s<5;++s){
      int vo = lane + 64*s;
      if (vo<VO){ int vtx=vo/J, o=vo-vtx*J; hb1[wv][r4][vtx*JP+o] = bf2f(cr[vo])*aC[vo] + cC[vo]; }
    }
  }
  asm volatile("s_waitcnt lgkmcnt(0)" ::: "memory");
  #pragma unroll
  for (int r4=0;r4<4;++r4){
    const int row = wv*4 + r4;
    #pragma unroll
    for (int s=0;s<5;++s){
      int vo = lane + 64*s;
      if (vo<VO){
        int vtx=vo/J, o=vo-vtx*J;
        unsigned m = ADJM[vtx];
        float a = 0.f;
        while (m){ int u=__ffs(m)-1; m&=m-1; a += hb1[wv][r4][u*JP+o]; }
        a = a>0.f ? a : 0.f;
        size_t gi = (size_t)(rowBase+row)*VO + vo;
        if (RESID)  a += F[gi];
        if (WRITEF) F[gi] = a;
        if (CONV){
          int idx = (row*576 + vtx*32 + o) ^ ((row&7)<<3);
          hb2[idx] = f2bf(a);
        } else {
          outF[gi] = a;
        }
      }
    }
  }
  if (!CONV) return;
  __syncthreads();

  for (int v=wv; v<J; v+=4){
    const int aidx = (lo*576 + v*32 + oc*8) ^ ((lo&7)<<3);
    bf16x8 a  = *(const bf16x8*)&hb2[aidx];
    bf16x8 bA = *(const bf16x8*)(wfA_g + ((size_t)v*64 + lane)*8);
    bf16x8 bB = {0,0,0,0,0,0,0,0};
    if (lo==0) bB = *(const bf16x8*)(wfB_g + ((size_t)v*4 + oc)*8);
    f32x4 acc0 = (f32x4){0.f,0.f,0.f,0.f};
    f32x4 acc1 = (f32x4){0.f,0.f,0.f,0.f};
    acc0 = __builtin_amdgcn_mfma_f32_16x16x32_bf16(a, bA, acc0, 0,0,0);
    acc1 = __builtin_amdgcn_mfma_f32_16x16x32_bf16(a, bB, acc1, 0,0,0);

    const float bias0 = bb[v*J+lo];
    const float bias1 = bb[v*J+16];
    float s0=0.f,q0=0.f,s1=0.f,q1=0.f;
    #pragma unroll
    for (int r=0;r<4;++r){
      const int row = rowBase + oc*4 + r;
      const float h0 = acc0[r] + bias0;
      Cout[(size_t)row*VO + v*J + lo] = f2bf(h0);
      s0 += h0; q0 += h0*h0;
      if (lo==0){
        const float h1 = acc1[r] + bias1;
        Cout[(size_t)row*VO + v*J + 16] = f2bf(h1);
        s1 += h1; q1 += h1*h1;
      }
    }
    s0 += __shfl_xor(s0,16); s0 += __shfl_xor(s0,32);
    q0 += __shfl_xor(q0,16); q0 += __shfl_xor(q0,32);
    s1 += __shfl_xor(s1,16); s1 += __shfl_xor(s1,32);
    q1 += __shfl_xor(q1,16); q1 += __shfl_xor(q1,32);
    if (lane < 16){ atomicAdd(&ssum[v*J+lo], s0); atomicAdd(&ssq[v*J+lo], q0); }
    if (lane == 0){ atomicAdd(&ssum[v*J+16], s1); atomicAdd(&ssq[v*J+16], q1); }
  }
  __syncthreads();
  const int rep = blockIdx.x & 7;
  for (int i=tid;i<VO;i+=256){
    atomicAdd(&statN[rep*512+i],        ssum[i]);
    atomicAdd(&statN[4096 + rep*512+i], ssq[i]);
  }
}

extern "C" void kernel_launch(void* const* d_in, const int* in_sizes, int n_in,
                              void* d_out, int out_size, void* d_ws, size_t ws_size,
                              hipStream_t stream)
{
  (void)in_sizes; (void)n_in; (void)out_size; (void)ws_size;
  const float* img = (const float*)d_in[0];
  const float* W0  = (const float*)d_in[1];
  const float* b0  = (const float*)d_in[2];
  const float* g0  = (const float*)d_in[3];
  const float* be0 = (const float*)d_in[4];
  const float* Wr  = (const float*)d_in[5];
  const float* br  = (const float*)d_in[6];
  const float* gr  = (const float*)d_in[7];
  const float* ber = (const float*)d_in[8];

  float* ws = (float*)d_ws;
  float* ST = ws;                                        // 73728 floats
  unsigned short* Wp  = (unsigned short*)(ws + 73728);   // 591872 ush (300000 f reserved)
  unsigned short* WfA = (unsigned short*)(ws + 73728 + 300000);   // 69632 ush
  unsigned short* WfB = WfA + 8*17*64*8;                          //  4352 ush (40000 f reserved)
  unsigned short* Ca = (unsigned short*)(ws + 73728 + 300000 + 40000);   // NB*VO ush
  unsigned short* Cb = Ca + (size_t)NB*VO;                               // NB*VO ush
  float* F  = ws + 73728 + 300000 + 40000 + (size_t)NB*VO;               // NB*VO f32
  float* out = (float*)d_out;

  zero_stats<<<72,256,0,stream>>>(ST, 9*8192);
  wconv_kernel<<<136,256,0,stream>>>(W0, Wp);
  wfrag_kernel<<<34,256,0,stream>>>(Wr, WfA, WfB);

  conv0_kernel<<<256,512,0,stream>>>(img, Wp, b0, Ca, ST);

  #define STG(j) (ST + (j)*8192)
  #define WFA(s) (WfA + (size_t)(s)*17*64*8)
  #define WFB(s) (WfB + (size_t)(s)*17*4*8)
  chain_kernel<0,1,1><<<512,256,0,stream>>>(Ca, Cb, F, nullptr, STG(0), g0,      be0,
                                            WFA(0), WFB(0), br+0*VO, STG(1));
  chain_kernel<0,0,1><<<512,256,0,stream>>>(Cb, Ca, F, nullptr, STG(1), gr+0*VO, ber+0*VO,
                                            WFA(1), WFB(1), br+1*VO, STG(2));
  chain_kernel<1,1,1><<<512,256,0,stream>>>(Ca, Cb, F, nullptr, STG(2), gr+1*VO, ber+1*VO,
                                            WFA(2), WFB(2), br+2*VO, STG(3));
  chain_kernel<0,0,1><<<512,256,0,stream>>>(Cb, Ca, F, nullptr, STG(3), gr+2*VO, ber+2*VO,
                                            WFA(3), WFB(3), br+3*VO, STG(4));
  chain_kernel<1,1,1><<<512,256,0,stream>>>(Ca, Cb, F, nullptr, STG(4), gr+3*VO, ber+3*VO,
                                            WFA(4), WFB(4), br+4*VO, STG(5));
  chain_kernel<0,0,1><<<512,256,0,stream>>>(Cb, Ca, F, nullptr, STG(5), gr+4*VO, ber+4*VO,
                                            WFA(5), WFB(5), br+5*VO, STG(6));
  chain_kernel<1,1,1><<<512,256,0,stream>>>(Ca, Cb, F, nullptr, STG(6), gr+5*VO, ber+5*VO,
                                            WFA(6), WFB(6), br+6*VO, STG(7));
  chain_kernel<0,0,1><<<512,256,0,stream>>>(Cb, Ca, F, nullptr, STG(7), gr+6*VO, ber+6*VO,
                                            WFA(7), WFB(7), br+7*VO, STG(8));
  chain_kernel<1,0,0><<<512,256,0,stream>>>(Ca, nullptr, F, out, STG(8), gr+7*VO, ber+7*VO,
                                            nullptr, nullptr, nullptr, nullptr);
  #undef STG
  #undef WFA
  #undef WFB
}